// Round 1
// baseline (248.896 us; speedup 1.0000x reference)
//
#include <hip/hip_runtime.h>
#include <stdint.h>

// Quant4Linear: out[16,28672] = x[16,8192] @ dequant(qweight) ; W[i,o]=q[i,o]*s[o]-z[o]
// out = (x @ q) * s - sum(x)*z + bias
//
// Design (round 1):
//  - f16 MFMA 16x16x32, x split hi/lo (two passes share the B fragment) for fp32-grade accuracy.
//  - One packed int32 word == one lane's 8 consecutive-k B-fragment elements (perfect match).
//  - wave = 128 cols (8 x 16-col tiles, A-frag reused 8x) x K-chunk 512.
//  - grid = 224 col-groups x 16 K-chunks = 3584 one-wave blocks = exactly 14 blocks/CU.
//  - K-split partials -> unsafeAtomicAdd (native global_atomic_add_f32) onto an output
//    pre-initialized with bias - sumx*z by q4l_init.

#define IN_F    8192
#define OUT_F   28672
#define NTOK    16

#define NREP    8                       // 16-col tiles per wave
#define COLS_PER_WAVE (NREP * 16)       // 128
#define NCG     (OUT_F / COLS_PER_WAVE) // 224
#define KSPLIT  16
#define KCHUNK  (IN_F / KSPLIT)         // 512
#define STEPS   (KCHUNK / 32)           // 16 MFMA K-steps per wave

typedef __attribute__((ext_vector_type(8))) _Float16 f16x8;
typedef __attribute__((ext_vector_type(4))) float    f32x4;

// ---------------------------------------------------------------------------
// init: out[t,o] = bias[o] - sumx[t]*zeros[o]   (sumx computed redundantly per block;
// x is L2/L3-resident so the redundancy is ~57MB of L2 reads ~ 1.7us)
__global__ __launch_bounds__(256) void q4l_init(
    const float* __restrict__ x,
    const float* __restrict__ zeros,
    const float* __restrict__ bias,
    float* __restrict__ out)
{
    __shared__ float s_sum[NTOK];
    const int tid  = threadIdx.x;
    const int wid  = tid >> 6;
    const int lane = tid & 63;

    for (int t = wid; t < NTOK; t += 4) {
        const float4* xr = (const float4*)(x + (size_t)t * IN_F);
        float p = 0.f;
        for (int i = lane; i < IN_F / 4; i += 64) {
            float4 v = xr[i];
            p += (v.x + v.y) + (v.z + v.w);
        }
        #pragma unroll
        for (int off = 32; off; off >>= 1) p += __shfl_down(p, off, 64);
        if (lane == 0) s_sum[t] = p;
    }
    __syncthreads();

    const int o = blockIdx.x * 256 + tid;   // grid = OUT_F/256 = 112 blocks
    const float b = bias[o];
    const float z = zeros[o];
    #pragma unroll
    for (int t = 0; t < NTOK; ++t)
        out[(size_t)t * OUT_F + o] = fmaf(-s_sum[t], z, b);
}

// ---------------------------------------------------------------------------
// main GEMM: one wave per block.
__global__ __launch_bounds__(64, 4) void q4l_main(
    const float* __restrict__ x,
    const uint32_t* __restrict__ qw,
    const float* __restrict__ scales,
    float* __restrict__ out)
{
    const int lane  = threadIdx.x;     // 0..63
    const int col16 = lane & 15;       // col within 16-tile == token row for A
    const int krow  = lane >> 4;       // 0..3  k-subblock

    const int bid = blockIdx.x;
    const int cg  = bid % NCG;         // column group (0..223)
    const int kc  = bid / NCG;         // K-chunk     (0..15)

    const uint32_t obase = (uint32_t)cg * COLS_PER_WAVE;
    const uint32_t w0    = (uint32_t)kc * (KCHUNK / 8);   // starting packed-word row

    // B element offset for (step s, tile t): (w0 + 4s + krow)*OUT_F + obase + t*16 + col16
    const uint32_t boff0 = (w0 + (uint32_t)krow) * OUT_F + obase + (uint32_t)col16;
    // A: x[col16][kc*KCHUNK + 32s + 8*krow + j]
    const float* xbase = x + (size_t)col16 * IN_F + (uint32_t)kc * KCHUNK + 8u * (uint32_t)krow;

    f32x4 acc[NREP];
    #pragma unroll
    for (int t = 0; t < NREP; ++t) acc[t] = (f32x4){0.f, 0.f, 0.f, 0.f};

    uint32_t bw[NREP];
    float4 xa, xb;

    // prologue: load step 0
    #pragma unroll
    for (int t = 0; t < NREP; ++t) bw[t] = qw[boff0 + (uint32_t)t * 16u];
    xa = *(const float4*)(xbase);
    xb = *(const float4*)(xbase + 4);

    #pragma unroll
    for (int s = 0; s < STEPS; ++s) {
        // stash current step's data
        uint32_t cb[NREP];
        #pragma unroll
        for (int t = 0; t < NREP; ++t) cb[t] = bw[t];
        const float4 ca0 = xa, ca1 = xb;

        // prefetch next step (1-deep; 3.5 waves/SIMD cover the rest of the latency)
        if (s + 1 < STEPS) {
            const uint32_t off = boff0 + (uint32_t)(s + 1) * 4u * OUT_F;
            #pragma unroll
            for (int t = 0; t < NREP; ++t) bw[t] = qw[off + (uint32_t)t * 16u];
            xa = *(const float4*)(xbase + (s + 1) * 32);
            xb = *(const float4*)(xbase + (s + 1) * 32 + 4);
        }

        // A fragments: hi = f16(x), lo = f16(x - hi)  -> exact-ish fp32 when summed
        const float cx[8] = {ca0.x, ca0.y, ca0.z, ca0.w, ca1.x, ca1.y, ca1.z, ca1.w};
        f16x8 ahi, alo;
        #pragma unroll
        for (int j = 0; j < 8; ++j) {
            const float v = cx[j];
            const _Float16 h = (_Float16)v;
            ahi[j] = h;
            alo[j] = (_Float16)(v - (float)h);
        }

        // per 16-col tile: unpack word -> 8 f16 nibbles, two MFMAs (hi, lo) into same acc
        #pragma unroll
        for (int t = 0; t < NREP; ++t) {
            const uint32_t w = cb[t];
            f16x8 bq;
            #pragma unroll
            for (int j = 0; j < 8; ++j)
                bq[j] = (_Float16)((w >> (4 * j)) & 15u);
            acc[t] = __builtin_amdgcn_mfma_f32_16x16x32_f16(ahi, bq, acc[t], 0, 0, 0);
            acc[t] = __builtin_amdgcn_mfma_f32_16x16x32_f16(alo, bq, acc[t], 0, 0, 0);
        }
    }

    // epilogue: out[4*krow + r][obase + 16t + col16] += s[o] * acc[t][r]
    #pragma unroll
    for (int t = 0; t < NREP; ++t) {
        const uint32_t o  = obase + (uint32_t)t * 16u + (uint32_t)col16;
        const float    sc = scales[o];
        #pragma unroll
        for (int r = 0; r < 4; ++r) {
            const uint32_t row = (uint32_t)krow * 4u + (uint32_t)r;
            unsafeAtomicAdd(&out[(size_t)row * OUT_F + o], sc * acc[t][r]);
        }
    }
}

// ---------------------------------------------------------------------------
extern "C" void kernel_launch(void* const* d_in, const int* in_sizes, int n_in,
                              void* d_out, int out_size, void* d_ws, size_t ws_size,
                              hipStream_t stream)
{
    const float*    x      = (const float*)   d_in[0];
    const uint32_t* qweight= (const uint32_t*)d_in[1];
    const float*    scales = (const float*)   d_in[2];
    const float*    zeros  = (const float*)   d_in[3];
    const float*    bias   = (const float*)   d_in[4];
    float* out = (float*)d_out;

    q4l_init<<<OUT_F / 256, 256, 0, stream>>>(x, zeros, bias, out);
    q4l_main<<<NCG * KSPLIT, 64, 0, stream>>>(x, qweight, scales, out);
}

// Round 4
// 183.719 us; speedup vs baseline: 1.3548x; 1.3548x over previous
//
#include <hip/hip_runtime.h>
#include <stdint.h>

// Quant4Linear fused kernel (round 4 = round 3 + cvt_pkrtz type fix).
// out[t,o] = s[o]*(x@q)[t,o] - sumx[t]*z[o] + bias[o]
//
//  - Single kernel, no atomics, no init pass, no d_ws.
//  - f16 MFMA 16x16x32; x split hi/lo (hi = mantissa-truncated f32, exact in f16;
//    lo = x - hi exact; packed with v_cvt_pkrtz). Two MFMAs share each B fragment.
//  - Magic-bias int4 unpack: (w>>sh)&0x000F000F | 0x64006400 -> f16 pair (1024+q).
//    1024 offset folds into epilogue: out = s*acc - (1024*s+z)*sumx + bias.
//    Nibble scramble {0,4,1,5,2,6,3,7} absorbed by permuting A-fragment packing.
//  - sumx computed BY MFMA (ones-column B) so it is consistent with what the
//    matrix pipe accumulated -> the 1024-amplified term cancels exactly.
//  - Grid: 256 blocks (1/CU) x 8 waves. Block owns 112 cols (7 tiles); waves
//    split K 8x1024; partials reduced via LDS. 2-deep B prefetch.

#define IN_F   8192
#define OUT_F  28672
#define NTOK   16
#define NREP   7                         // 16-col tiles per block
#define WAVES  8
#define NCG    (OUT_F / (NREP * 16))     // 256 blocks
#define KCHUNK (IN_F / WAVES)            // 1024 per wave
#define STEPS  (KCHUNK / 32)             // 32 MFMA K-steps per wave

typedef __attribute__((ext_vector_type(8))) _Float16 f16x8;
typedef __attribute__((ext_vector_type(2))) __fp16   fp16x2;  // cvt_pkrtz return type
typedef __attribute__((ext_vector_type(4))) float    f32x4;

__global__ __launch_bounds__(512, 2) void q4l_fused(
    const float* __restrict__ x,
    const uint32_t* __restrict__ qw,
    const float* __restrict__ scales,
    const float* __restrict__ zeros,
    const float* __restrict__ bias,
    float* __restrict__ out)
{
    __shared__ float lds_acc[WAVES][NREP][64][4];   // 57344 B
    __shared__ float lds_sxw[WAVES][NTOK];          //   512 B
    __shared__ float lds_sumx[NTOK];                //    64 B

    const int tid   = threadIdx.x;
    const int wid   = tid >> 6;
    const int lane  = tid & 63;
    const int col16 = lane & 15;
    const int krow  = lane >> 4;

    const uint32_t obase = (uint32_t)blockIdx.x * (NREP * 16u);
    const uint32_t w0    = (uint32_t)wid * (KCHUNK / 8);   // starting packed-word row

    // B word offset for (step s, tile t): (w0 + 4s + krow)*OUT_F + obase + 16t + col16
    const uint32_t boff0 = (w0 + (uint32_t)krow) * OUT_F + obase + (uint32_t)col16;
    // A: x[col16][wid*KCHUNK + 32s + 8*krow + j]
    const float* xbase = x + (size_t)col16 * IN_F + (uint32_t)wid * KCHUNK + 8u * (uint32_t)krow;

    f32x4 acc[NREP];
    #pragma unroll
    for (int t = 0; t < NREP; ++t) acc[t] = (f32x4){0.f, 0.f, 0.f, 0.f};
    f32x4 acc1 = (f32x4){0.f, 0.f, 0.f, 0.f};      // ones-column: per-token sum of A

    f16x8 ones;
    #pragma unroll
    for (int j = 0; j < 8; ++j) ones[j] = (_Float16)1.0f;

    uint32_t bw0[NREP], bw1[NREP];
    float4 xa, xb;

    // prologue: B for steps 0 and 1, A for step 0
    #pragma unroll
    for (int t = 0; t < NREP; ++t) bw0[t] = qw[boff0 + (uint32_t)t * 16u];
    #pragma unroll
    for (int t = 0; t < NREP; ++t) bw1[t] = qw[boff0 + 4u * OUT_F + (uint32_t)t * 16u];
    xa = *(const float4*)(xbase);
    xb = *(const float4*)(xbase + 4);

#define Q4L_STEP(CUR, S)                                                      \
    do {                                                                      \
        uint32_t cw[NREP];                                                    \
        _Pragma("unroll")                                                     \
        for (int t = 0; t < NREP; ++t) cw[t] = CUR[t];                        \
        const float4 ca0 = xa, ca1 = xb;                                      \
        if ((S) + 2 < STEPS) {  /* 2-deep B prefetch */                       \
            const uint32_t off = boff0 + (uint32_t)((S) + 2) * 4u * OUT_F;    \
            _Pragma("unroll")                                                 \
            for (int t = 0; t < NREP; ++t)                                    \
                CUR[t] = qw[off + (uint32_t)t * 16u];                         \
        }                                                                     \
        if ((S) + 1 < STEPS) {  /* 1-deep A prefetch (L2-resident) */         \
            xa = *(const float4*)(xbase + ((S) + 1) * 32);                    \
            xb = *(const float4*)(xbase + ((S) + 1) * 32 + 4);                \
        }                                                                     \
        const float cx[8] = {ca0.x, ca0.y, ca0.z, ca0.w,                      \
                             ca1.x, ca1.y, ca1.z, ca1.w};                     \
        /* A pack, permuted {0,4,1,5,2,6,3,7} to match nibble pair order:     \
           hi = f32 truncated to f16 mantissa (exact in f16), lo = v - hi */  \
        union { f16x8 v; fp16x2 h[4]; } AH, AL;                               \
        {                                                                     \
            const int PRM[8] = {0, 4, 1, 5, 2, 6, 3, 7};                      \
            float hi[8], lo[8];                                               \
            _Pragma("unroll")                                                 \
            for (int j = 0; j < 8; ++j) {                                     \
                const float v = cx[PRM[j]];                                   \
                const float h = __uint_as_float(__float_as_uint(v) & 0xFFFFE000u); \
                hi[j] = h;                                                    \
                lo[j] = v - h;                                                \
            }                                                                 \
            _Pragma("unroll")                                                 \
            for (int j = 0; j < 4; ++j) {                                     \
                AH.h[j] = __builtin_amdgcn_cvt_pkrtz(hi[2*j], hi[2*j+1]);     \
                AL.h[j] = __builtin_amdgcn_cvt_pkrtz(lo[2*j], lo[2*j+1]);     \
            }                                                                 \
        }                                                                     \
        _Pragma("unroll")                                                     \
        for (int t = 0; t < NREP; ++t) {                                      \
            const uint32_t w = cw[t];                                         \
            union { f16x8 v; uint32_t u[4]; } B;                              \
            B.u[0] = ((w      ) & 0x000F000Fu) | 0x64006400u;                 \
            B.u[1] = ((w >> 4 ) & 0x000F000Fu) | 0x64006400u;                 \
            B.u[2] = ((w >> 8 ) & 0x000F000Fu) | 0x64006400u;                 \
            B.u[3] = ((w >> 12) & 0x000F000Fu) | 0x64006400u;                 \
            acc[t] = __builtin_amdgcn_mfma_f32_16x16x32_f16(AH.v, B.v, acc[t], 0, 0, 0); \
            acc[t] = __builtin_amdgcn_mfma_f32_16x16x32_f16(AL.v, B.v, acc[t], 0, 0, 0); \
        }                                                                     \
        /* per-token running sum of (hi+lo) via ones-column MFMA */           \
        acc1 = __builtin_amdgcn_mfma_f32_16x16x32_f16(AH.v, ones, acc1, 0, 0, 0); \
        acc1 = __builtin_amdgcn_mfma_f32_16x16x32_f16(AL.v, ones, acc1, 0, 0, 0); \
    } while (0)

    for (int s = 0; s < STEPS; s += 2) {
        Q4L_STEP(bw0, s);
        Q4L_STEP(bw1, s + 1);
    }
#undef Q4L_STEP

    // ---- block-level K reduction via LDS ----
    #pragma unroll
    for (int t = 0; t < NREP; ++t)
        *(f32x4*)&lds_acc[wid][t][lane][0] = acc[t];
    if (col16 == 0) {
        #pragma unroll
        for (int r = 0; r < 4; ++r)
            lds_sxw[wid][krow * 4 + r] = acc1[r];   // token = 4*krow + r
    }
    __syncthreads();

    f32x4 tot = (f32x4){0.f, 0.f, 0.f, 0.f};
    if (wid < NREP) {
        #pragma unroll
        for (int w = 0; w < WAVES; ++w) {
            const f32x4 p = *(const f32x4*)&lds_acc[w][wid][lane][0];
            tot += p;
        }
    } else if (lane < NTOK) {
        // wave 7: reduce per-token A sums across the 8 K-chunks
        float s = 0.f;
        #pragma unroll
        for (int w = 0; w < WAVES; ++w) s += lds_sxw[w][lane];
        lds_sumx[lane] = s;
    }
    __syncthreads();

    if (wid < NREP) {
        // tile wid: out row = 4*krow + r, col = obase + 16*wid + col16
        const uint32_t o  = obase + (uint32_t)wid * 16u + (uint32_t)col16;
        const float sc = scales[o];
        const float zz = zeros[o];
        const float bb = bias[o];
        const float corr = fmaf(1024.f, sc, zz);   // 1024*s + z
        #pragma unroll
        for (int r = 0; r < 4; ++r) {
            const int token = krow * 4 + r;
            const float sx = lds_sumx[token];
            out[(size_t)token * OUT_F + o] = fmaf(sc, tot[r], fmaf(-corr, sx, bb));
        }
    }
}

// ---------------------------------------------------------------------------
extern "C" void kernel_launch(void* const* d_in, const int* in_sizes, int n_in,
                              void* d_out, int out_size, void* d_ws, size_t ws_size,
                              hipStream_t stream)
{
    const float*    x       = (const float*)   d_in[0];
    const uint32_t* qweight = (const uint32_t*)d_in[1];
    const float*    scales  = (const float*)   d_in[2];
    const float*    zeros   = (const float*)   d_in[3];
    const float*    bias    = (const float*)   d_in[4];
    float* out = (float*)d_out;

    q4l_fused<<<NCG, 512, 0, stream>>>(x, qweight, scales, zeros, bias, out);
}

// Round 6
// 182.976 us; speedup vs baseline: 1.3603x; 1.0041x over previous
//
#include <hip/hip_runtime.h>
#include <stdint.h>

// Quant4Linear fused kernel (round 6 = round 5 resubmit; GPU timeout last round).
// out[t,o] = s[o]*(x@q)[t,o] - sumx[t]*z[o] + bias[o]
//
//  - Single kernel, no atomics, no init pass, no d_ws.
//  - f16 MFMA 16x16x32; x split hi/lo (hi = mantissa-truncated f32, exact in f16;
//    lo = x - hi exact; packed with v_cvt_pkrtz). Two MFMAs share each B fragment.
//  - Magic-bias int4 unpack: (w>>sh)&0x000F000F | 0x64006400 -> f16 pair (1024+q),
//    then SUBTRACT 1024.0 in f16 (v_pk_add_f16, exact) -> B = q directly.
//    No 1024-amplified accumulator -> no cancellation noise (r4 absmax 0.25 -> ~0.03).
//  - sumx computed BY MFMA (ones-column B), used only for the z-term.
//  - Grid: 256 blocks (1/CU) x 8 waves. Block owns 112 cols (7 tiles); waves
//    split K 8x1024; partials reduced via LDS. 2-deep B prefetch.

#define IN_F   8192
#define OUT_F  28672
#define NTOK   16
#define NREP   7                         // 16-col tiles per block
#define WAVES  8
#define NCG    (OUT_F / (NREP * 16))     // 256 blocks
#define KCHUNK (IN_F / WAVES)            // 1024 per wave
#define STEPS  (KCHUNK / 32)             // 32 MFMA K-steps per wave

typedef __attribute__((ext_vector_type(8))) _Float16 f16x8;
typedef __attribute__((ext_vector_type(2))) __fp16   fp16x2;  // cvt_pkrtz return type
typedef __attribute__((ext_vector_type(4))) float    f32x4;

__global__ __launch_bounds__(512, 2) void q4l_fused(
    const float* __restrict__ x,
    const uint32_t* __restrict__ qw,
    const float* __restrict__ scales,
    const float* __restrict__ zeros,
    const float* __restrict__ bias,
    float* __restrict__ out)
{
    __shared__ float lds_acc[WAVES][NREP][64][4];   // 57344 B
    __shared__ float lds_sxw[WAVES][NTOK];          //   512 B
    __shared__ float lds_sumx[NTOK];                //    64 B

    const int tid   = threadIdx.x;
    const int wid   = tid >> 6;
    const int lane  = tid & 63;
    const int col16 = lane & 15;
    const int krow  = lane >> 4;

    const uint32_t obase = (uint32_t)blockIdx.x * (NREP * 16u);
    const uint32_t w0    = (uint32_t)wid * (KCHUNK / 8);   // starting packed-word row

    // B word offset for (step s, tile t): (w0 + 4s + krow)*OUT_F + obase + 16t + col16
    const uint32_t boff0 = (w0 + (uint32_t)krow) * OUT_F + obase + (uint32_t)col16;
    // A: x[col16][wid*KCHUNK + 32s + 8*krow + j]
    const float* xbase = x + (size_t)col16 * IN_F + (uint32_t)wid * KCHUNK + 8u * (uint32_t)krow;

    f32x4 acc[NREP];
    #pragma unroll
    for (int t = 0; t < NREP; ++t) acc[t] = (f32x4){0.f, 0.f, 0.f, 0.f};
    f32x4 acc1 = (f32x4){0.f, 0.f, 0.f, 0.f};      // ones-column: per-token sum of A

    f16x8 ones, c1024;
    #pragma unroll
    for (int j = 0; j < 8; ++j) { ones[j] = (_Float16)1.0f; c1024[j] = (_Float16)1024.0f; }

    uint32_t bw0[NREP], bw1[NREP];
    float4 xa, xb;

    // prologue: B for steps 0 and 1, A for step 0
    #pragma unroll
    for (int t = 0; t < NREP; ++t) bw0[t] = qw[boff0 + (uint32_t)t * 16u];
    #pragma unroll
    for (int t = 0; t < NREP; ++t) bw1[t] = qw[boff0 + 4u * OUT_F + (uint32_t)t * 16u];
    xa = *(const float4*)(xbase);
    xb = *(const float4*)(xbase + 4);

#define Q4L_STEP(CUR, S)                                                      \
    do {                                                                      \
        uint32_t cw[NREP];                                                    \
        _Pragma("unroll")                                                     \
        for (int t = 0; t < NREP; ++t) cw[t] = CUR[t];                        \
        const float4 ca0 = xa, ca1 = xb;                                      \
        if ((S) + 2 < STEPS) {  /* 2-deep B prefetch */                       \
            const uint32_t off = boff0 + (uint32_t)((S) + 2) * 4u * OUT_F;    \
            _Pragma("unroll")                                                 \
            for (int t = 0; t < NREP; ++t)                                    \
                CUR[t] = qw[off + (uint32_t)t * 16u];                         \
        }                                                                     \
        if ((S) + 1 < STEPS) {  /* 1-deep A prefetch (L2-resident) */         \
            xa = *(const float4*)(xbase + ((S) + 1) * 32);                    \
            xb = *(const float4*)(xbase + ((S) + 1) * 32 + 4);                \
        }                                                                     \
        const float cx[8] = {ca0.x, ca0.y, ca0.z, ca0.w,                      \
                             ca1.x, ca1.y, ca1.z, ca1.w};                     \
        /* A pack, permuted {0,4,1,5,2,6,3,7} to match nibble pair order:     \
           hi = f32 truncated to f16 mantissa (exact in f16), lo = v - hi */  \
        union { f16x8 v; fp16x2 h[4]; } AH, AL;                               \
        {                                                                     \
            const int PRM[8] = {0, 4, 1, 5, 2, 6, 3, 7};                      \
            float hi[8], lo[8];                                               \
            _Pragma("unroll")                                                 \
            for (int j = 0; j < 8; ++j) {                                     \
                const float v = cx[PRM[j]];                                   \
                const float h = __uint_as_float(__float_as_uint(v) & 0xFFFFE000u); \
                hi[j] = h;                                                    \
                lo[j] = v - h;                                                \
            }                                                                 \
            _Pragma("unroll")                                                 \
            for (int j = 0; j < 4; ++j) {                                     \
                AH.h[j] = __builtin_amdgcn_cvt_pkrtz(hi[2*j], hi[2*j+1]);     \
                AL.h[j] = __builtin_amdgcn_cvt_pkrtz(lo[2*j], lo[2*j+1]);     \
            }                                                                 \
        }                                                                     \
        _Pragma("unroll")                                                     \
        for (int t = 0; t < NREP; ++t) {                                      \
            const uint32_t w = cw[t];                                         \
            union { f16x8 v; uint32_t u[4]; } B;                              \
            B.u[0] = ((w      ) & 0x000F000Fu) | 0x64006400u;                 \
            B.u[1] = ((w >> 4 ) & 0x000F000Fu) | 0x64006400u;                 \
            B.u[2] = ((w >> 8 ) & 0x000F000Fu) | 0x64006400u;                 \
            B.u[3] = ((w >> 12) & 0x000F000Fu) | 0x64006400u;                 \
            const f16x8 q16 = B.v - c1024;   /* exact: (1024+q)-1024 = q */   \
            acc[t] = __builtin_amdgcn_mfma_f32_16x16x32_f16(AH.v, q16, acc[t], 0, 0, 0); \
            acc[t] = __builtin_amdgcn_mfma_f32_16x16x32_f16(AL.v, q16, acc[t], 0, 0, 0); \
        }                                                                     \
        /* per-token running sum of (hi+lo) via ones-column MFMA */           \
        acc1 = __builtin_amdgcn_mfma_f32_16x16x32_f16(AH.v, ones, acc1, 0, 0, 0); \
        acc1 = __builtin_amdgcn_mfma_f32_16x16x32_f16(AL.v, ones, acc1, 0, 0, 0); \
    } while (0)

    for (int s = 0; s < STEPS; s += 2) {
        Q4L_STEP(bw0, s);
        Q4L_STEP(bw1, s + 1);
    }
#undef Q4L_STEP

    // ---- block-level K reduction via LDS ----
    #pragma unroll
    for (int t = 0; t < NREP; ++t)
        *(f32x4*)&lds_acc[wid][t][lane][0] = acc[t];
    if (col16 == 0) {
        #pragma unroll
        for (int r = 0; r < 4; ++r)
            lds_sxw[wid][krow * 4 + r] = acc1[r];   // token = 4*krow + r
    }
    __syncthreads();

    f32x4 tot = (f32x4){0.f, 0.f, 0.f, 0.f};
    if (wid < NREP) {
        #pragma unroll
        for (int w = 0; w < WAVES; ++w) {
            const f32x4 p = *(const f32x4*)&lds_acc[w][wid][lane][0];
            tot += p;
        }
    } else if (lane < NTOK) {
        // wave 7: reduce per-token A sums across the 8 K-chunks
        float s = 0.f;
        #pragma unroll
        for (int w = 0; w < WAVES; ++w) s += lds_sxw[w][lane];
        lds_sumx[lane] = s;
    }
    __syncthreads();

    if (wid < NREP) {
        // tile wid: out row = 4*krow + r, col = obase + 16*wid + col16
        const uint32_t o  = obase + (uint32_t)wid * 16u + (uint32_t)col16;
        const float sc = scales[o];
        const float zz = zeros[o];
        const float bb = bias[o];
        #pragma unroll
        for (int r = 0; r < 4; ++r) {
            const int token = krow * 4 + r;
            const float sx = lds_sumx[token];
            out[(size_t)token * OUT_F + o] = fmaf(sc, tot[r], fmaf(-zz, sx, bb));
        }
    }
}

// ---------------------------------------------------------------------------
extern "C" void kernel_launch(void* const* d_in, const int* in_sizes, int n_in,
                              void* d_out, int out_size, void* d_ws, size_t ws_size,
                              hipStream_t stream)
{
    const float*    x       = (const float*)   d_in[0];
    const uint32_t* qweight = (const uint32_t*)d_in[1];
    const float*    scales  = (const float*)   d_in[2];
    const float*    zeros   = (const float*)   d_in[3];
    const float*    bias    = (const float*)   d_in[4];
    float* out = (float*)d_out;

    q4l_fused<<<NCG, 512, 0, stream>>>(x, qweight, scales, zeros, bias, out);
}

// Round 7
// 180.862 us; speedup vs baseline: 1.3762x; 1.0117x over previous
//
#include <hip/hip_runtime.h>
#include <stdint.h>

// Quant4Linear fused kernel (round 7 = round 6 + 3-deep B prefetch probe).
// out[t,o] = s[o]*(x@q)[t,o] - sumx[t]*z[o] + bias[o]
//
//  - Single kernel, no atomics, no init pass, no d_ws.
//  - f16 MFMA 16x16x32; x split hi/lo (hi = mantissa-truncated f32, exact in f16;
//    lo = x - hi exact; packed with v_cvt_pkrtz). Two MFMAs share each B fragment.
//  - Magic-bias int4 unpack: (w>>sh)&0x000F000F | 0x64006400 -> f16 pair (1024+q),
//    then SUBTRACT 1024.0 in f16 (v_pk_add_f16, exact) -> B = q directly.
//  - sumx computed BY MFMA (ones-column B), used only for the z-term.
//  - Grid: 256 blocks (1/CU) x 8 waves. Block owns 112 cols (7 tiles); waves
//    split K 8x1024; partials reduced via LDS.
//  - NEW: 3-deep B prefetch (bw[3][NREP] rotation, fully-unrolled loop so the
//    s%3 index is compile-time -> registers, not scratch). Covers the case where
//    steady-state per-wave step time (~650cy at 2 waves/SIMD) leaves 2-deep
//    prefetch (<900cy HBM latency) with a per-step stall bubble.

#define IN_F   8192
#define OUT_F  28672
#define NTOK   16
#define NREP   7                         // 16-col tiles per block
#define WAVES  8
#define NCG    (OUT_F / (NREP * 16))     // 256 blocks
#define KCHUNK (IN_F / WAVES)            // 1024 per wave
#define STEPS  (KCHUNK / 32)             // 32 MFMA K-steps per wave

typedef __attribute__((ext_vector_type(8))) _Float16 f16x8;
typedef __attribute__((ext_vector_type(2))) __fp16   fp16x2;  // cvt_pkrtz return type
typedef __attribute__((ext_vector_type(4))) float    f32x4;

__global__ __launch_bounds__(512, 2) void q4l_fused(
    const float* __restrict__ x,
    const uint32_t* __restrict__ qw,
    const float* __restrict__ scales,
    const float* __restrict__ zeros,
    const float* __restrict__ bias,
    float* __restrict__ out)
{
    __shared__ float lds_acc[WAVES][NREP][64][4];   // 57344 B
    __shared__ float lds_sxw[WAVES][NTOK];          //   512 B
    __shared__ float lds_sumx[NTOK];                //    64 B

    const int tid   = threadIdx.x;
    const int wid   = tid >> 6;
    const int lane  = tid & 63;
    const int col16 = lane & 15;
    const int krow  = lane >> 4;

    const uint32_t obase = (uint32_t)blockIdx.x * (NREP * 16u);
    const uint32_t w0    = (uint32_t)wid * (KCHUNK / 8);   // starting packed-word row

    // B word offset for (step s, tile t): (w0 + 4s + krow)*OUT_F + obase + 16t + col16
    const uint32_t boff0 = (w0 + (uint32_t)krow) * OUT_F + obase + (uint32_t)col16;
    // A: x[col16][wid*KCHUNK + 32s + 8*krow + j]
    const float* xbase = x + (size_t)col16 * IN_F + (uint32_t)wid * KCHUNK + 8u * (uint32_t)krow;

    f32x4 acc[NREP];
    #pragma unroll
    for (int t = 0; t < NREP; ++t) acc[t] = (f32x4){0.f, 0.f, 0.f, 0.f};
    f32x4 acc1 = (f32x4){0.f, 0.f, 0.f, 0.f};      // ones-column: per-token sum of A

    f16x8 ones, c1024;
    #pragma unroll
    for (int j = 0; j < 8; ++j) { ones[j] = (_Float16)1.0f; c1024[j] = (_Float16)1024.0f; }

    uint32_t bw[3][NREP];
    float4 xa, xb;

    // prologue: B for steps 0,1,2; A for step 0
    #pragma unroll
    for (int p = 0; p < 3; ++p)
        #pragma unroll
        for (int t = 0; t < NREP; ++t)
            bw[p][t] = qw[boff0 + (uint32_t)p * 4u * OUT_F + (uint32_t)t * 16u];
    xa = *(const float4*)(xbase);
    xb = *(const float4*)(xbase + 4);

    #pragma unroll
    for (int s = 0; s < STEPS; ++s) {
        // stash current step's B words (buffer s%3 — compile-time after unroll)
        uint32_t cw[NREP];
        #pragma unroll
        for (int t = 0; t < NREP; ++t) cw[t] = bw[s % 3][t];
        const float4 ca0 = xa, ca1 = xb;

        if (s + 3 < STEPS) {  // 3-deep B prefetch into the freed buffer
            const uint32_t off = boff0 + (uint32_t)(s + 3) * 4u * OUT_F;
            #pragma unroll
            for (int t = 0; t < NREP; ++t)
                bw[s % 3][t] = qw[off + (uint32_t)t * 16u];
        }
        if (s + 1 < STEPS) {  // 1-deep A prefetch (L2-resident)
            xa = *(const float4*)(xbase + (s + 1) * 32);
            xb = *(const float4*)(xbase + (s + 1) * 32 + 4);
        }

        const float cx[8] = {ca0.x, ca0.y, ca0.z, ca0.w,
                             ca1.x, ca1.y, ca1.z, ca1.w};
        // A pack, permuted {0,4,1,5,2,6,3,7} to match nibble pair order:
        // hi = f32 truncated to f16 mantissa (exact in f16), lo = v - hi
        union { f16x8 v; fp16x2 h[4]; } AH, AL;
        {
            const int PRM[8] = {0, 4, 1, 5, 2, 6, 3, 7};
            float hi[8], lo[8];
            #pragma unroll
            for (int j = 0; j < 8; ++j) {
                const float v = cx[PRM[j]];
                const float h = __uint_as_float(__float_as_uint(v) & 0xFFFFE000u);
                hi[j] = h;
                lo[j] = v - h;
            }
            #pragma unroll
            for (int j = 0; j < 4; ++j) {
                AH.h[j] = __builtin_amdgcn_cvt_pkrtz(hi[2*j], hi[2*j+1]);
                AL.h[j] = __builtin_amdgcn_cvt_pkrtz(lo[2*j], lo[2*j+1]);
            }
        }

        #pragma unroll
        for (int t = 0; t < NREP; ++t) {
            const uint32_t w = cw[t];
            union { f16x8 v; uint32_t u[4]; } B;
            B.u[0] = ((w      ) & 0x000F000Fu) | 0x64006400u;
            B.u[1] = ((w >> 4 ) & 0x000F000Fu) | 0x64006400u;
            B.u[2] = ((w >> 8 ) & 0x000F000Fu) | 0x64006400u;
            B.u[3] = ((w >> 12) & 0x000F000Fu) | 0x64006400u;
            const f16x8 q16 = B.v - c1024;   // exact: (1024+q)-1024 = q
            acc[t] = __builtin_amdgcn_mfma_f32_16x16x32_f16(AH.v, q16, acc[t], 0, 0, 0);
            acc[t] = __builtin_amdgcn_mfma_f32_16x16x32_f16(AL.v, q16, acc[t], 0, 0, 0);
        }
        // per-token running sum of (hi+lo) via ones-column MFMA
        acc1 = __builtin_amdgcn_mfma_f32_16x16x32_f16(AH.v, ones, acc1, 0, 0, 0);
        acc1 = __builtin_amdgcn_mfma_f32_16x16x32_f16(AL.v, ones, acc1, 0, 0, 0);
    }

    // ---- block-level K reduction via LDS ----
    #pragma unroll
    for (int t = 0; t < NREP; ++t)
        *(f32x4*)&lds_acc[wid][t][lane][0] = acc[t];
    if (col16 == 0) {
        #pragma unroll
        for (int r = 0; r < 4; ++r)
            lds_sxw[wid][krow * 4 + r] = acc1[r];   // token = 4*krow + r
    }
    __syncthreads();

    f32x4 tot = (f32x4){0.f, 0.f, 0.f, 0.f};
    if (wid < NREP) {
        #pragma unroll
        for (int w = 0; w < WAVES; ++w) {
            const f32x4 p = *(const f32x4*)&lds_acc[w][wid][lane][0];
            tot += p;
        }
    } else if (lane < NTOK) {
        // wave 7: reduce per-token A sums across the 8 K-chunks
        float s = 0.f;
        #pragma unroll
        for (int w = 0; w < WAVES; ++w) s += lds_sxw[w][lane];
        lds_sumx[lane] = s;
    }
    __syncthreads();

    if (wid < NREP) {
        // tile wid: out row = 4*krow + r, col = obase + 16*wid + col16
        const uint32_t o  = obase + (uint32_t)wid * 16u + (uint32_t)col16;
        const float sc = scales[o];
        const float zz = zeros[o];
        const float bb = bias[o];
        #pragma unroll
        for (int r = 0; r < 4; ++r) {
            const int token = krow * 4 + r;
            const float sx = lds_sumx[token];
            out[(size_t)token * OUT_F + o] = fmaf(sc, tot[r], fmaf(-zz, sx, bb));
        }
    }
}

// ---------------------------------------------------------------------------
extern "C" void kernel_launch(void* const* d_in, const int* in_sizes, int n_in,
                              void* d_out, int out_size, void* d_ws, size_t ws_size,
                              hipStream_t stream)
{
    const float*    x       = (const float*)   d_in[0];
    const uint32_t* qweight = (const uint32_t*)d_in[1];
    const float*    scales  = (const float*)   d_in[2];
    const float*    zeros   = (const float*)   d_in[3];
    const float*    bias    = (const float*)   d_in[4];
    float* out = (float*)d_out;

    q4l_fused<<<NCG, 512, 0, stream>>>(x, qweight, scales, zeros, bias, out);
}